// Round 2
// baseline (1092.820 us; speedup 1.0000x reference)
//
#include <hip/hip_runtime.h>
#include <math.h>

// Polarisation: Thole-damped dipole field + diagonal 1/alpha term.
// out[n] = mu[n]/pol[n] + sum_{e: src=n} [ lam3/r^3 * mu[dst] - 3*lam5/r^5 * (vec.mu[dst]) * vec ]
//
// R2: per-XCD partial accumulators + WORKGROUP-scope atomics.
// R1 showed WRITE_SIZE == 19.2M atomics * 32B exactly: device-scope fp32
// atomicAdd executes at the memory side (~20 G atomics/s wall). Workgroup-scope
// atomics emit cacheable global_atomic_add_f32 executed at the local XCD's TCC;
// giving each XCD a private buffer (indexed by HW_REG_XCC_ID) keeps the RMW
// L2-resident and correct (no cross-XCD sharing). Dispatch-release fence writes
// back dirty L2 before the reduce kernel.

#define INV_BOHR   1.8897261254578281f   // 1 / 0.52917721067
#define INV_BOHR3  (INV_BOHR*INV_BOHR*INV_BOHR)
#define A_MUTUAL   0.39f
#define NXCD       8

// ---- q precompute: q[i] = pol_bohr^(-1/6)  (u_ij = r * q[s] * q[d]) ----
__global__ void pol_q_kernel(const float* __restrict__ pol_ang,
                             float* __restrict__ q, int n_nodes) {
    int i = blockIdx.x * blockDim.x + threadIdx.x;
    if (i >= n_nodes) return;
    q[i] = powf(pol_ang[i] * INV_BOHR3, -1.0f / 6.0f);
}

// ---- edge kernel, fast path: wg-scope atomics into per-XCD partials ----
__global__ void pol_edge_xcd(const int*   __restrict__ src,
                             const int*   __restrict__ dst,
                             const float* __restrict__ dist,
                             const float* __restrict__ vec,
                             const float* __restrict__ q,
                             const float* __restrict__ mu,
                             float* __restrict__ partial,   // [NXCD][3*N]
                             int n_edges, int n3) {
    int e = blockIdx.x * blockDim.x + threadIdx.x;
    if (e >= n_edges) return;

    unsigned xcd;
    asm volatile("s_getreg_b32 %0, hwreg(HW_REG_XCC_ID)" : "=s"(xcd));
    float* p = partial + (size_t)(xcd & (NXCD - 1)) * (unsigned)n3;

    // Edge streams: nontemporal so they don't evict hot q/mu/partial L2 lines.
    int   s   = __builtin_nontemporal_load(&src[e]);
    int   d   = __builtin_nontemporal_load(&dst[e]);
    float rij = __builtin_nontemporal_load(&dist[e]) * INV_BOHR;
    float vx  = __builtin_nontemporal_load(&vec[3*e + 0]) * INV_BOHR;
    float vy  = __builtin_nontemporal_load(&vec[3*e + 1]) * INV_BOHR;
    float vz  = __builtin_nontemporal_load(&vec[3*e + 2]) * INV_BOHR;

    float u   = rij * q[s] * q[d];
    float au3 = A_MUTUAL * u * u * u;

    // expm1-based, cancellation-free Thole lambdas.
    float em1  = expm1f(-au3);
    float lam3 = -em1;
    float lam5 = -(em1 + au3 * (em1 + 1.0f));

    float inv_r  = 1.0f / rij;
    float inv_r2 = inv_r * inv_r;
    float inv_r3 = inv_r2 * inv_r;
    float inv_r5 = inv_r3 * inv_r2;

    float mx = mu[3*d + 0];
    float my = mu[3*d + 1];
    float mz = mu[3*d + 2];

    float dot = vx*mx + vy*my + vz*mz;
    float c3  = lam3 * inv_r3;
    float c5  = 3.0f * lam5 * inv_r5 * dot;

    __hip_atomic_fetch_add(&p[3*s + 0], c3*mx - c5*vx, __ATOMIC_RELAXED, __HIP_MEMORY_SCOPE_WORKGROUP);
    __hip_atomic_fetch_add(&p[3*s + 1], c3*my - c5*vy, __ATOMIC_RELAXED, __HIP_MEMORY_SCOPE_WORKGROUP);
    __hip_atomic_fetch_add(&p[3*s + 2], c3*mz - c5*vz, __ATOMIC_RELAXED, __HIP_MEMORY_SCOPE_WORKGROUP);
}

// ---- reduce: out = mu/pol + sum over XCD partials ----
__global__ void pol_reduce(const float* __restrict__ partial,  // [NXCD][3*N]
                           const float* __restrict__ pol_ang,
                           const float* __restrict__ mu,
                           float* __restrict__ out, int n_nodes) {
    int i = blockIdx.x * blockDim.x + threadIdx.x;
    if (i >= n_nodes) return;
    int n3 = 3 * n_nodes;
    float ip = 1.0f / (pol_ang[i] * INV_BOHR3);
    #pragma unroll
    for (int c = 0; c < 3; ++c) {
        float acc = mu[3*i + c] * ip;
        #pragma unroll
        for (int x = 0; x < NXCD; ++x)
            acc += partial[(size_t)x * n3 + 3*i + c];
        out[3*i + c] = acc;
    }
}

// ---- fallback path (R1): device-scope atomics straight into out ----
__global__ void pol_node_kernel(const float* __restrict__ pol_ang,
                                const float* __restrict__ mu,
                                float* __restrict__ out,
                                float* __restrict__ q, int n_nodes) {
    int i = blockIdx.x * blockDim.x + threadIdx.x;
    if (i >= n_nodes) return;
    float pol = pol_ang[i] * INV_BOHR3;
    float ip  = 1.0f / pol;
    out[3*i + 0] = mu[3*i + 0] * ip;
    out[3*i + 1] = mu[3*i + 1] * ip;
    out[3*i + 2] = mu[3*i + 2] * ip;
    q[i] = powf(pol, -1.0f / 6.0f);
}

__global__ void pol_edge_kernel(const int*   __restrict__ src,
                                const int*   __restrict__ dst,
                                const float* __restrict__ dist,
                                const float* __restrict__ vec,
                                const float* __restrict__ q,
                                const float* __restrict__ mu,
                                float* __restrict__ out, int n_edges) {
    int e = blockIdx.x * blockDim.x + threadIdx.x;
    if (e >= n_edges) return;
    int s = src[e], d = dst[e];
    float rij = dist[e] * INV_BOHR;
    float u   = rij * q[s] * q[d];
    float au3 = A_MUTUAL * u * u * u;
    float em1  = expm1f(-au3);
    float lam3 = -em1;
    float lam5 = -(em1 + au3 * (em1 + 1.0f));
    float inv_r  = 1.0f / rij;
    float inv_r2 = inv_r * inv_r;
    float inv_r3 = inv_r2 * inv_r;
    float inv_r5 = inv_r3 * inv_r2;
    float vx = vec[3*e+0] * INV_BOHR, vy = vec[3*e+1] * INV_BOHR, vz = vec[3*e+2] * INV_BOHR;
    float mx = mu[3*d+0], my = mu[3*d+1], mz = mu[3*d+2];
    float dot = vx*mx + vy*my + vz*mz;
    float c3 = lam3 * inv_r3;
    float c5 = 3.0f * lam5 * inv_r5 * dot;
    atomicAdd(&out[3*s + 0], c3*mx - c5*vx);
    atomicAdd(&out[3*s + 1], c3*my - c5*vy);
    atomicAdd(&out[3*s + 2], c3*mz - c5*vz);
}

extern "C" void kernel_launch(void* const* d_in, const int* in_sizes, int n_in,
                              void* d_out, int out_size, void* d_ws, size_t ws_size,
                              hipStream_t stream) {
    // inputs: 0 species(unused) 1 edge_src 2 edge_dst 3 distances 4 vec 5 polarisability 6 mu
    const int*   edge_src = (const int*)d_in[1];
    const int*   edge_dst = (const int*)d_in[2];
    const float* dist     = (const float*)d_in[3];
    const float* vec      = (const float*)d_in[4];
    const float* pol      = (const float*)d_in[5];
    const float* mu       = (const float*)d_in[6];

    float* out = (float*)d_out;
    int n_nodes = in_sizes[5];
    int n_edges = in_sizes[1];
    int n3 = 3 * n_nodes;

    size_t partial_bytes = (size_t)NXCD * n3 * sizeof(float);
    size_t need = partial_bytes + (size_t)n_nodes * sizeof(float);

    if (ws_size >= need) {
        float* partial = (float*)d_ws;
        float* q       = (float*)((char*)d_ws + partial_bytes);

        hipMemsetAsync(partial, 0, partial_bytes, stream);
        pol_q_kernel<<<(n_nodes + 255) / 256, 256, 0, stream>>>(pol, q, n_nodes);
        pol_edge_xcd<<<(n_edges + 255) / 256, 256, 0, stream>>>(edge_src, edge_dst, dist, vec,
                                                                q, mu, partial, n_edges, n3);
        pol_reduce<<<(n_nodes + 255) / 256, 256, 0, stream>>>(partial, pol, mu, out, n_nodes);
    } else {
        float* q = (float*)d_ws;
        pol_node_kernel<<<(n_nodes + 255) / 256, 256, 0, stream>>>(pol, mu, out, q, n_nodes);
        pol_edge_kernel<<<(n_edges + 255) / 256, 256, 0, stream>>>(edge_src, edge_dst, dist, vec,
                                                                   q, mu, out, n_edges);
    }
}

// Round 4
// 563.890 us; speedup vs baseline: 1.9380x; 1.9380x over previous
//
#include <hip/hip_runtime.h>
#include <math.h>

// Polarisation: Thole-damped dipole field + diagonal 1/alpha term.
// out[n] = mu[n]/pol[n] + sum_{e: src=n} [ lam3/r^3 * mu[dst] - 3*lam5/r^5 * (vec.mu[dst]) * vec ]
//
// R4 (= R3 resubmit + EPB 8192->2048 for occupancy): bucket-scatter +
// LDS-accumulate. R1/R2 proved every global fp32 atomicAdd is a 32B
// memory-side transaction (~20G atomics/s wall) regardless of scope. So:
// partition edges into 256 node-range buckets (per-block LDS histogram + ONE
// global int atomic per (block,bucket) to reserve a private contiguous
// range), write 16B contribution records, then one block per bucket
// accumulates records into LDS (ds_add_f32) and writes out coalesced.
// Global fp32 atomics: 19.2M -> 0.

#define INV_BOHR   1.8897261254578281f   // 1 / 0.52917721067
#define INV_BOHR3  (INV_BOHR*INV_BOHR*INV_BOHR)
#define A_MUTUAL   0.39f
#define NB         256                   // buckets
#define EPB        2048                  // edges per scatter block (391 blk/chunk @ NCHUNK=8)
#define MAX_NPB    1024                  // max nodes per bucket (LDS limit)

// ---- node init: out = mu/pol ; q = pol_bohr^(-1/6) ----
__global__ void pol_node_kernel(const float* __restrict__ pol_ang,
                                const float* __restrict__ mu,
                                float* __restrict__ out,
                                float* __restrict__ q, int n_nodes) {
    int i = blockIdx.x * blockDim.x + threadIdx.x;
    if (i >= n_nodes) return;
    float pol = pol_ang[i] * INV_BOHR3;
    float ip  = 1.0f / pol;
    out[3*i + 0] = mu[3*i + 0] * ip;
    out[3*i + 1] = mu[3*i + 1] * ip;
    out[3*i + 2] = mu[3*i + 2] * ip;
    q[i] = powf(pol, -1.0f / 6.0f);          // u_ij = r * q[s] * q[d]
}

__device__ __forceinline__ void thole_contrib(
        float rij, float vx, float vy, float vz,
        float qs, float qd, float mx, float my, float mz,
        float& cx, float& cy, float& cz) {
    float u   = rij * qs * qd;
    float au3 = A_MUTUAL * u * u * u;
    // expm1-based, cancellation-free Thole lambdas.
    float em1  = expm1f(-au3);
    float lam3 = -em1;
    float lam5 = -(em1 + au3 * (em1 + 1.0f));
    float inv_r  = 1.0f / rij;
    float inv_r2 = inv_r * inv_r;
    float inv_r3 = inv_r2 * inv_r;
    float inv_r5 = inv_r3 * inv_r2;
    float dot = vx*mx + vy*my + vz*mz;
    float c3  = lam3 * inv_r3;
    float c5  = 3.0f * lam5 * inv_r5 * dot;
    cx = c3*mx - c5*vx;
    cy = c3*my - c5*vy;
    cz = c3*mz - c5*vz;
}

// ---- scatter: bucket edges' contributions into per-bucket record regions ----
__global__ __launch_bounds__(256)
void pol_scatter(const int*   __restrict__ src,
                 const int*   __restrict__ dst,
                 const float* __restrict__ dist,
                 const float* __restrict__ vec,
                 const float* __restrict__ q,
                 const float* __restrict__ mu,
                 float4*      __restrict__ records,   // [NB][cap]
                 int*         __restrict__ gcursor,   // [NB], zeroed per chunk
                 int e0, int e1, int npb, int cap) {
    __shared__ int hist[NB];
    __shared__ int curs[NB];
    int tid = threadIdx.x;
    int eb0 = e0 + blockIdx.x * EPB;
    int eb1 = min(eb0 + EPB, e1);

    if (tid < NB) hist[tid] = 0;
    __syncthreads();

    // phase 1: local histogram (src chunk is 8KB — stays L2-hot for phase 2)
    for (int e = eb0 + tid; e < eb1; e += 256) {
        int s = src[e];
        atomicAdd(&hist[s / npb], 1);
    }
    __syncthreads();

    // reserve a private contiguous range per bucket (one global int atomic)
    if (tid < NB) {
        int c = hist[tid];
        curs[tid] = (c > 0) ? atomicAdd(&gcursor[tid], c) : 0;
    }
    __syncthreads();

    // phase 2: compute contribution, write record into reserved slots
    for (int e = eb0 + tid; e < eb1; e += 256) {
        int   s   = src[e];
        int   d   = __builtin_nontemporal_load(&dst[e]);
        float rij = __builtin_nontemporal_load(&dist[e]) * INV_BOHR;
        float vx  = __builtin_nontemporal_load(&vec[3*e + 0]) * INV_BOHR;
        float vy  = __builtin_nontemporal_load(&vec[3*e + 1]) * INV_BOHR;
        float vz  = __builtin_nontemporal_load(&vec[3*e + 2]) * INV_BOHR;

        float cx, cy, cz;
        thole_contrib(rij, vx, vy, vz, q[s], q[d],
                      mu[3*d + 0], mu[3*d + 1], mu[3*d + 2], cx, cy, cz);

        int b   = s / npb;
        int rel = atomicAdd(&curs[b], 1);      // LDS atomic
        if (rel < cap)   // 8-sigma cap: statistically impossible to overflow
            records[(size_t)b * cap + rel] = make_float4(cx, cy, cz, __int_as_float(s));
    }
}

// ---- gather: one block per bucket; LDS-accumulate records; out += acc ----
__global__ __launch_bounds__(512)
void pol_gather(const float4* __restrict__ records,
                const int*    __restrict__ gcursor,
                float*        __restrict__ out,
                int cap, int npb, int n_nodes) {
    __shared__ float acc[3 * MAX_NPB];
    int j   = blockIdx.x;
    int tid = threadIdx.x;
    int n0  = j * npb;
    int nn  = min(npb, n_nodes - n0);
    if (nn <= 0) return;

    for (int k = tid; k < 3 * nn; k += 512) acc[k] = 0.0f;
    __syncthreads();

    int cnt = min(gcursor[j], cap);
    const float4* rec = records + (size_t)j * cap;
    for (int i = tid; i < cnt; i += 512) {
        float4 r = rec[i];
        int l = __float_as_int(r.w) - n0;
        atomicAdd(&acc[3*l + 0], r.x);   // ds_add_f32: LDS atomic, no global RMW
        atomicAdd(&acc[3*l + 1], r.y);
        atomicAdd(&acc[3*l + 2], r.z);
    }
    __syncthreads();

    float* o = out + (size_t)3 * n0;
    for (int k = tid; k < 3 * nn; k += 512) o[k] += acc[k];
}

// ---- fallback (R1): device-scope atomics straight into out ----
__global__ void pol_edge_kernel(const int*   __restrict__ src,
                                const int*   __restrict__ dst,
                                const float* __restrict__ dist,
                                const float* __restrict__ vec,
                                const float* __restrict__ q,
                                const float* __restrict__ mu,
                                float* __restrict__ out, int n_edges) {
    int e = blockIdx.x * blockDim.x + threadIdx.x;
    if (e >= n_edges) return;
    int s = src[e], d = dst[e];
    float rij = dist[e] * INV_BOHR;
    float cx, cy, cz;
    thole_contrib(rij, vec[3*e+0]*INV_BOHR, vec[3*e+1]*INV_BOHR, vec[3*e+2]*INV_BOHR,
                  q[s], q[d], mu[3*d+0], mu[3*d+1], mu[3*d+2], cx, cy, cz);
    atomicAdd(&out[3*s + 0], cx);
    atomicAdd(&out[3*s + 1], cy);
    atomicAdd(&out[3*s + 2], cz);
}

extern "C" void kernel_launch(void* const* d_in, const int* in_sizes, int n_in,
                              void* d_out, int out_size, void* d_ws, size_t ws_size,
                              hipStream_t stream) {
    // inputs: 0 species(unused) 1 edge_src 2 edge_dst 3 distances 4 vec 5 polarisability 6 mu
    const int*   edge_src = (const int*)d_in[1];
    const int*   edge_dst = (const int*)d_in[2];
    const float* dist     = (const float*)d_in[3];
    const float* vec      = (const float*)d_in[4];
    const float* pol      = (const float*)d_in[5];
    const float* mu       = (const float*)d_in[6];

    float* out   = (float*)d_out;
    int n_nodes  = in_sizes[5];
    int n_edges  = in_sizes[1];
    int npb      = (n_nodes + NB - 1) / NB;     // nodes per bucket

    // pick smallest NCHUNK whose record buffer fits in ws (ws >= 20MB proven by R2)
    size_t reserve = (size_t)n_nodes * sizeof(float) + 4096; // q + gcursor + pad
    int    nch = -1;
    long long cap = 0;
    size_t rec_bytes = 0;
    for (int c = 1; c <= 16; c *= 2) {
        long long chunk = ((long long)n_edges + c - 1) / c;
        long long m     = (chunk + NB - 1) / NB;
        long long cp    = m + 8 * (long long)(sqrt((double)m) + 1.0) + 64;
        size_t rb = (size_t)NB * (size_t)cp * sizeof(float4);
        if (rb + reserve <= ws_size) { nch = c; cap = cp; rec_bytes = rb; break; }
    }

    if (nch > 0 && npb <= MAX_NPB) {
        float4* records = (float4*)d_ws;
        int*    gcursor = (int*)((char*)d_ws + rec_bytes);
        float*  q       = (float*)((char*)d_ws + rec_bytes + 1024);

        pol_node_kernel<<<(n_nodes + 255) / 256, 256, 0, stream>>>(pol, mu, out, q, n_nodes);

        long long chunk = ((long long)n_edges + nch - 1) / nch;
        for (int r = 0; r < nch; ++r) {
            int e0 = (int)(r * chunk);
            int e1 = (int)min((long long)n_edges, e0 + chunk);
            if (e0 >= e1) break;
            hipMemsetAsync(gcursor, 0, NB * sizeof(int), stream);
            int nblk = (e1 - e0 + EPB - 1) / EPB;
            pol_scatter<<<nblk, 256, 0, stream>>>(edge_src, edge_dst, dist, vec, q, mu,
                                                  records, gcursor, e0, e1, npb, (int)cap);
            pol_gather<<<NB, 512, 0, stream>>>(records, gcursor, out, (int)cap, npb, n_nodes);
        }
    } else {
        // fallback: R1 atomic path (needs only q in ws)
        float* q = (float*)d_ws;
        pol_node_kernel<<<(n_nodes + 255) / 256, 256, 0, stream>>>(pol, mu, out, q, n_nodes);
        pol_edge_kernel<<<(n_edges + 255) / 256, 256, 0, stream>>>(edge_src, edge_dst, dist, vec,
                                                                   q, mu, out, n_edges);
    }
}

// Round 6
// 426.511 us; speedup vs baseline: 2.5622x; 1.3221x over previous
//
#include <hip/hip_runtime.h>
#include <math.h>

// Polarisation: Thole-damped dipole field + diagonal 1/alpha term.
// out[n] = mu[n]/pol[n] + sum_{e: src=n} [ lam3/r^3 * mu[dst] - 3*lam5/r^5 * (vec.mu[dst]) * vec ]
//
// R6 (= R5 + compile fix: nontemporal loads via clang ext_vector f32x4, not
// HIP_vector_type float4): scatter writes were the R4 wall (WRITE_SIZE =
// 6.4M x 32B: scattered 16B record stores cost a 32B memory-side transaction
// + RFO fetch each). Fix: per-block in-LDS bucket sort so record writes are
// contiguous runs per bucket -> full-line coalesced stores. Gather gets
// 4x-unrolled independent loads. Global fp32 atomics: 0.

#define INV_BOHR   1.8897261254578281f   // 1 / 0.52917721067
#define INV_BOHR3  (INV_BOHR*INV_BOHR*INV_BOHR)
#define A_MUTUAL   0.39f
#define NB         256                   // buckets
#define EPB        4096                  // edges per scatter block
#define SCT        512                   // scatter threads
#define GAT        1024                  // gather threads
#define MAX_NPB    1024                  // max nodes per bucket (LDS limit)
#define GC_STRIDE  16                    // gcursor padding: 16 ints = 64B/counter

typedef float f32x4 __attribute__((ext_vector_type(4)));  // nontemporal-compatible 16B vector

// ---- node init: out = mu/pol ; q = pol_bohr^(-1/6) ----
__global__ void pol_node_kernel(const float* __restrict__ pol_ang,
                                const float* __restrict__ mu,
                                float* __restrict__ out,
                                float* __restrict__ q, int n_nodes) {
    int i = blockIdx.x * blockDim.x + threadIdx.x;
    if (i >= n_nodes) return;
    float pol = pol_ang[i] * INV_BOHR3;
    float ip  = 1.0f / pol;
    out[3*i + 0] = mu[3*i + 0] * ip;
    out[3*i + 1] = mu[3*i + 1] * ip;
    out[3*i + 2] = mu[3*i + 2] * ip;
    q[i] = powf(pol, -1.0f / 6.0f);          // u_ij = r * q[s] * q[d]
}

__device__ __forceinline__ void thole_contrib(
        float rij, float vx, float vy, float vz,
        float qs, float qd, float mx, float my, float mz,
        float& cx, float& cy, float& cz) {
    float u   = rij * qs * qd;
    float au3 = A_MUTUAL * u * u * u;
    // expm1-based, cancellation-free Thole lambdas.
    float em1  = expm1f(-au3);
    float lam3 = -em1;
    float lam5 = -(em1 + au3 * (em1 + 1.0f));
    float inv_r  = 1.0f / rij;
    float inv_r2 = inv_r * inv_r;
    float inv_r3 = inv_r2 * inv_r;
    float inv_r5 = inv_r3 * inv_r2;
    float dot = vx*mx + vy*my + vz*mz;
    float c3  = lam3 * inv_r3;
    float c5  = 3.0f * lam5 * inv_r5 * dot;
    cx = c3*mx - c5*vx;
    cy = c3*my - c5*vy;
    cz = c3*mz - c5*vz;
}

// ---- scatter: in-LDS bucket sort, then coalesced per-bucket-run writes ----
__global__ __launch_bounds__(SCT, 4)
void pol_scatter(const int*   __restrict__ src,
                 const int*   __restrict__ dst,
                 const float* __restrict__ dist,
                 const float* __restrict__ vec,
                 const float* __restrict__ q,
                 const float* __restrict__ mu,
                 f32x4*       __restrict__ records,   // [NB][cap]
                 int*         __restrict__ gcursor,   // [NB*GC_STRIDE], zeroed
                 int e0, int e1, int npb, int cap) {
    __shared__ f32x4 stage[EPB];         // 64KB: bucket-sorted records
    __shared__ int hist[NB];
    __shared__ int lbase[NB];            // exclusive prefix of hist
    __shared__ int scan[NB];
    __shared__ int lcur[NB];             // placement cursors
    __shared__ int gbase[NB];            // reserved global base (per bucket)

    int tid = threadIdx.x;
    int eb0 = e0 + blockIdx.x * EPB;
    int eb1 = min(eb0 + EPB, e1);
    int nrec = eb1 - eb0;
    if (nrec <= 0) return;

    if (tid < NB) hist[tid] = 0;
    __syncthreads();

    // phase 1: histogram of src buckets; keep src in regs
    int s_reg[EPB / SCT];
    #pragma unroll
    for (int j = 0; j < EPB / SCT; ++j) {
        int e = eb0 + j * SCT + tid;
        int s = (e < eb1) ? src[e] : -1;
        s_reg[j] = s;
        if (s >= 0) atomicAdd(&hist[s / npb], 1);
    }
    __syncthreads();

    // phase 2: exclusive scan (Hillis-Steele) + global range reservation
    if (tid < NB) scan[tid] = hist[tid];
    __syncthreads();
    for (int off = 1; off < NB; off <<= 1) {
        int v = 0;
        if (tid < NB && tid >= off) v = scan[tid - off];
        __syncthreads();
        if (tid < NB) scan[tid] += v;
        __syncthreads();
    }
    if (tid < NB) {
        int lb = scan[tid] - hist[tid];
        lbase[tid] = lb;
        lcur[tid]  = lb;
        gbase[tid] = (hist[tid] > 0) ? atomicAdd(&gcursor[tid * GC_STRIDE], hist[tid]) : 0;
    }
    __syncthreads();

    // phase 3: compute contribution, place bucket-sorted into LDS stage
    #pragma unroll
    for (int j = 0; j < EPB / SCT; ++j) {
        int s = s_reg[j];
        if (s < 0) continue;
        int e = eb0 + j * SCT + tid;
        int   d   = __builtin_nontemporal_load(&dst[e]);
        float rij = __builtin_nontemporal_load(&dist[e]) * INV_BOHR;
        float vx  = __builtin_nontemporal_load(&vec[3*e + 0]) * INV_BOHR;
        float vy  = __builtin_nontemporal_load(&vec[3*e + 1]) * INV_BOHR;
        float vz  = __builtin_nontemporal_load(&vec[3*e + 2]) * INV_BOHR;

        float cx, cy, cz;
        thole_contrib(rij, vx, vy, vz, q[s], q[d],
                      mu[3*d + 0], mu[3*d + 1], mu[3*d + 2], cx, cy, cz);

        int b = s / npb;
        int p = atomicAdd(&lcur[b], 1);            // LDS atomic
        f32x4 rec;
        rec.x = cx; rec.y = cy; rec.z = cz; rec.w = __int_as_float(s);
        stage[p] = rec;
    }
    __syncthreads();

    // phase 4: flat coalesced write-out; runs per bucket are contiguous
    for (int k = tid; k < nrec; k += SCT) {
        f32x4 f = stage[k];
        int s = __float_as_int(f.w);
        int b = s / npb;
        int slot = gbase[b] + (k - lbase[b]);
        if (slot < cap)   // 8-sigma cap: statistically impossible overflow
            records[(size_t)b * cap + slot] = f;
    }
}

// ---- gather: one block per bucket; LDS-accumulate; out += acc ----
__global__ __launch_bounds__(GAT, 4)
void pol_gather(const f32x4* __restrict__ records,
                const int*   __restrict__ gcursor,
                float*       __restrict__ out,
                int cap, int npb, int n_nodes) {
    __shared__ float acc[3 * MAX_NPB];
    int j   = blockIdx.x;
    int tid = threadIdx.x;
    int n0  = j * npb;
    int nn  = min(npb, n_nodes - n0);
    if (nn <= 0) return;

    for (int k = tid; k < 3 * nn; k += GAT) acc[k] = 0.0f;
    __syncthreads();

    int cnt = min(gcursor[j * GC_STRIDE], cap);
    const f32x4* rec = records + (size_t)j * cap;

    int i = tid;
    // 4x unroll: 4 independent loads in flight per wave
    for (; i + 3 * GAT < cnt; i += 4 * GAT) {
        f32x4 r0 = __builtin_nontemporal_load(&rec[i]);
        f32x4 r1 = __builtin_nontemporal_load(&rec[i + GAT]);
        f32x4 r2 = __builtin_nontemporal_load(&rec[i + 2 * GAT]);
        f32x4 r3 = __builtin_nontemporal_load(&rec[i + 3 * GAT]);
        int l0 = __float_as_int(r0.w) - n0;
        int l1 = __float_as_int(r1.w) - n0;
        int l2 = __float_as_int(r2.w) - n0;
        int l3 = __float_as_int(r3.w) - n0;
        atomicAdd(&acc[3*l0 + 0], r0.x); atomicAdd(&acc[3*l0 + 1], r0.y); atomicAdd(&acc[3*l0 + 2], r0.z);
        atomicAdd(&acc[3*l1 + 0], r1.x); atomicAdd(&acc[3*l1 + 1], r1.y); atomicAdd(&acc[3*l1 + 2], r1.z);
        atomicAdd(&acc[3*l2 + 0], r2.x); atomicAdd(&acc[3*l2 + 1], r2.y); atomicAdd(&acc[3*l2 + 2], r2.z);
        atomicAdd(&acc[3*l3 + 0], r3.x); atomicAdd(&acc[3*l3 + 1], r3.y); atomicAdd(&acc[3*l3 + 2], r3.z);
    }
    for (; i < cnt; i += GAT) {
        f32x4 r = __builtin_nontemporal_load(&rec[i]);
        int l = __float_as_int(r.w) - n0;
        atomicAdd(&acc[3*l + 0], r.x);
        atomicAdd(&acc[3*l + 1], r.y);
        atomicAdd(&acc[3*l + 2], r.z);
    }
    __syncthreads();

    float* o = out + (size_t)3 * n0;
    for (int k = tid; k < 3 * nn; k += GAT) o[k] += acc[k];
}

// ---- fallback (R1): device-scope atomics straight into out ----
__global__ void pol_edge_kernel(const int*   __restrict__ src,
                                const int*   __restrict__ dst,
                                const float* __restrict__ dist,
                                const float* __restrict__ vec,
                                const float* __restrict__ q,
                                const float* __restrict__ mu,
                                float* __restrict__ out, int n_edges) {
    int e = blockIdx.x * blockDim.x + threadIdx.x;
    if (e >= n_edges) return;
    int s = src[e], d = dst[e];
    float rij = dist[e] * INV_BOHR;
    float cx, cy, cz;
    thole_contrib(rij, vec[3*e+0]*INV_BOHR, vec[3*e+1]*INV_BOHR, vec[3*e+2]*INV_BOHR,
                  q[s], q[d], mu[3*d+0], mu[3*d+1], mu[3*d+2], cx, cy, cz);
    atomicAdd(&out[3*s + 0], cx);
    atomicAdd(&out[3*s + 1], cy);
    atomicAdd(&out[3*s + 2], cz);
}

extern "C" void kernel_launch(void* const* d_in, const int* in_sizes, int n_in,
                              void* d_out, int out_size, void* d_ws, size_t ws_size,
                              hipStream_t stream) {
    // inputs: 0 species(unused) 1 edge_src 2 edge_dst 3 distances 4 vec 5 polarisability 6 mu
    const int*   edge_src = (const int*)d_in[1];
    const int*   edge_dst = (const int*)d_in[2];
    const float* dist     = (const float*)d_in[3];
    const float* vec      = (const float*)d_in[4];
    const float* pol      = (const float*)d_in[5];
    const float* mu       = (const float*)d_in[6];

    float* out   = (float*)d_out;
    int n_nodes  = in_sizes[5];
    int n_edges  = in_sizes[1];
    int npb      = (n_nodes + NB - 1) / NB;     // nodes per bucket

    // pick smallest NCHUNK whose record buffer fits in ws (R4 proved NCHUNK=1 fits)
    size_t gc_bytes = (size_t)NB * GC_STRIDE * sizeof(int);         // 16KB padded cursors
    size_t reserve  = gc_bytes + (size_t)n_nodes * sizeof(float) + 4096;
    int    nch = -1;
    long long cap = 0;
    size_t rec_bytes = 0;
    for (int c = 1; c <= 16; c *= 2) {
        long long chunk = ((long long)n_edges + c - 1) / c;
        long long m     = (chunk + NB - 1) / NB;
        long long cp    = m + 8 * (long long)(sqrt((double)m) + 1.0) + 64;
        size_t rb = (size_t)NB * (size_t)cp * sizeof(f32x4);
        if (rb + reserve <= ws_size) { nch = c; cap = cp; rec_bytes = rb; break; }
    }

    if (nch > 0 && npb <= MAX_NPB) {
        f32x4* records = (f32x4*)d_ws;
        int*   gcursor = (int*)((char*)d_ws + rec_bytes);
        float* q       = (float*)((char*)d_ws + rec_bytes + gc_bytes);

        pol_node_kernel<<<(n_nodes + 255) / 256, 256, 0, stream>>>(pol, mu, out, q, n_nodes);

        long long chunk = ((long long)n_edges + nch - 1) / nch;
        for (int r = 0; r < nch; ++r) {
            int e0 = (int)(r * chunk);
            int e1 = (int)min((long long)n_edges, e0 + chunk);
            if (e0 >= e1) break;
            (void)hipMemsetAsync(gcursor, 0, gc_bytes, stream);
            int nblk = (e1 - e0 + EPB - 1) / EPB;
            pol_scatter<<<nblk, SCT, 0, stream>>>(edge_src, edge_dst, dist, vec, q, mu,
                                                  records, gcursor, e0, e1, npb, (int)cap);
            pol_gather<<<NB, GAT, 0, stream>>>(records, gcursor, out, (int)cap, npb, n_nodes);
        }
    } else {
        // fallback: R1 atomic path (needs only q in ws)
        float* q = (float*)d_ws;
        pol_node_kernel<<<(n_nodes + 255) / 256, 256, 0, stream>>>(pol, mu, out, q, n_nodes);
        pol_edge_kernel<<<(n_edges + 255) / 256, 256, 0, stream>>>(edge_src, edge_dst, dist, vec,
                                                                   q, mu, out, n_edges);
    }
}

// Round 7
// 403.837 us; speedup vs baseline: 2.7061x; 1.0561x over previous
//
#include <hip/hip_runtime.h>
#include <math.h>

// Polarisation: Thole-damped dipole field + diagonal 1/alpha term.
// out[n] = mu[n]/pol[n] + sum_{e: src=n} [ lam3/r^3 * mu[dst] - 3*lam5/r^5 * (vec.mu[dst]) * vec ]
//
// R7: R6's scatter was latency-bound (VALUBusy 15%, occ 36%, 1.3 TB/s).
// Fixes: (a) EPB 4096->2048 => 37.9KB LDS/block => 4 blocks/CU (32 waves, HW
// max); (b) fused qmu[n]={mu.xyz,q} float4 table => 1 dwordx4 gather per edge
// instead of 4-5 loads; (c) exact magic-div for s/npb (s<2^18); (d) gather
// MLP 4->8. Record writes stay bucket-sorted-in-LDS => coalesced (R6 win).

#define INV_BOHR   1.8897261254578281f   // 1 / 0.52917721067
#define INV_BOHR3  (INV_BOHR*INV_BOHR*INV_BOHR)
#define A_MUTUAL   0.39f
#define NB         256                   // buckets
#define EPB        2048                  // edges per scatter block
#define SCT        512                   // scatter threads (4 edges/thread)
#define GAT        1024                  // gather threads
#define MAX_NPB    1024                  // max nodes per bucket (LDS limit)
#define GC_STRIDE  16                    // gcursor padding: 64B/counter
#define MSHIFT     40                    // magic-div shift (exact: s<2^18, npb<2^14)

typedef float f32x4 __attribute__((ext_vector_type(4)));

__device__ __forceinline__ int bdiv(int s, unsigned magic) {
    return (int)(((unsigned long long)(unsigned)s * magic) >> MSHIFT);
}

// ---- node init: out = mu/pol ; qmu[n] = {mu.xyz, pol_bohr^(-1/6)} ----
__global__ void pol_node_kernel(const float* __restrict__ pol_ang,
                                const float* __restrict__ mu,
                                float* __restrict__ out,
                                f32x4* __restrict__ qmu, int n_nodes) {
    int i = blockIdx.x * blockDim.x + threadIdx.x;
    if (i >= n_nodes) return;
    float pol = pol_ang[i] * INV_BOHR3;
    float ip  = 1.0f / pol;
    float mx = mu[3*i + 0], my = mu[3*i + 1], mz = mu[3*i + 2];
    out[3*i + 0] = mx * ip;
    out[3*i + 1] = my * ip;
    out[3*i + 2] = mz * ip;
    f32x4 t; t.x = mx; t.y = my; t.z = mz; t.w = powf(pol, -1.0f / 6.0f);
    qmu[i] = t;
}

__device__ __forceinline__ void thole_contrib(
        float rij, float vx, float vy, float vz,
        float qs, float qd, float mx, float my, float mz,
        float& cx, float& cy, float& cz) {
    float u   = rij * qs * qd;
    float au3 = A_MUTUAL * u * u * u;
    // expm1-based, cancellation-free Thole lambdas.
    float em1  = expm1f(-au3);
    float lam3 = -em1;
    float lam5 = -(em1 + au3 * (em1 + 1.0f));
    float inv_r  = 1.0f / rij;
    float inv_r2 = inv_r * inv_r;
    float inv_r3 = inv_r2 * inv_r;
    float inv_r5 = inv_r3 * inv_r2;
    float dot = vx*mx + vy*my + vz*mz;
    float c3  = lam3 * inv_r3;
    float c5  = 3.0f * lam5 * inv_r5 * dot;
    cx = c3*mx - c5*vx;
    cy = c3*my - c5*vy;
    cz = c3*mz - c5*vz;
}

// ---- scatter: in-LDS bucket sort, then coalesced per-bucket-run writes ----
__global__ __launch_bounds__(SCT, 8)
void pol_scatter(const int*   __restrict__ src,
                 const int*   __restrict__ dst,
                 const float* __restrict__ dist,
                 const float* __restrict__ vec,
                 const f32x4* __restrict__ qmu,
                 f32x4*       __restrict__ records,   // [NB][cap]
                 int*         __restrict__ gcursor,   // [NB*GC_STRIDE], zeroed
                 int e0, int e1, int npb, int cap, unsigned magic) {
    __shared__ f32x4 stage[EPB];         // 32KB: bucket-sorted records
    __shared__ int hist[NB];
    __shared__ int lbase[NB];            // exclusive prefix of hist
    __shared__ int scan[NB];
    __shared__ int lcur[NB];             // placement cursors
    __shared__ int gbase[NB];            // reserved global base (per bucket)

    int tid = threadIdx.x;
    int eb0 = e0 + blockIdx.x * EPB;
    int eb1 = min(eb0 + EPB, e1);
    int nrec = eb1 - eb0;
    if (nrec <= 0) return;

    if (tid < NB) hist[tid] = 0;
    __syncthreads();

    // phase 1: histogram of src buckets; keep src in regs
    int s_reg[EPB / SCT];
    #pragma unroll
    for (int j = 0; j < EPB / SCT; ++j) {
        int e = eb0 + j * SCT + tid;
        int s = (e < eb1) ? __builtin_nontemporal_load(&src[e]) : -1;
        s_reg[j] = s;
        if (s >= 0) atomicAdd(&hist[bdiv(s, magic)], 1);
    }
    __syncthreads();

    // phase 2: exclusive scan (Hillis-Steele) + global range reservation
    if (tid < NB) scan[tid] = hist[tid];
    __syncthreads();
    for (int off = 1; off < NB; off <<= 1) {
        int v = 0;
        if (tid < NB && tid >= off) v = scan[tid - off];
        __syncthreads();
        if (tid < NB) scan[tid] += v;
        __syncthreads();
    }
    if (tid < NB) {
        int lb = scan[tid] - hist[tid];
        lbase[tid] = lb;
        lcur[tid]  = lb;
        gbase[tid] = (hist[tid] > 0) ? atomicAdd(&gcursor[tid * GC_STRIDE], hist[tid]) : 0;
    }
    __syncthreads();

    // phase 3: compute contribution, place bucket-sorted into LDS stage
    #pragma unroll
    for (int j = 0; j < EPB / SCT; ++j) {
        int s = s_reg[j];
        if (s < 0) continue;
        int e = eb0 + j * SCT + tid;
        int   d   = __builtin_nontemporal_load(&dst[e]);
        float rij = __builtin_nontemporal_load(&dist[e]) * INV_BOHR;
        float vx  = __builtin_nontemporal_load(&vec[3*e + 0]) * INV_BOHR;
        float vy  = __builtin_nontemporal_load(&vec[3*e + 1]) * INV_BOHR;
        float vz  = __builtin_nontemporal_load(&vec[3*e + 2]) * INV_BOHR;

        f32x4 md = qmu[d];               // one dwordx4 gather: mu.xyz + q
        float qs = qmu[s].w;             // one dword gather

        float cx, cy, cz;
        thole_contrib(rij, vx, vy, vz, qs, md.w, md.x, md.y, md.z, cx, cy, cz);

        int b = bdiv(s, magic);
        int p = atomicAdd(&lcur[b], 1);            // LDS atomic
        f32x4 rec;
        rec.x = cx; rec.y = cy; rec.z = cz; rec.w = __int_as_float(s);
        stage[p] = rec;
    }
    __syncthreads();

    // phase 4: flat coalesced write-out; runs per bucket are contiguous
    for (int k = tid; k < nrec; k += SCT) {
        f32x4 f = stage[k];
        int s = __float_as_int(f.w);
        int b = bdiv(s, magic);
        int slot = gbase[b] + (k - lbase[b]);
        if (slot < cap)   // 8-sigma cap: statistically impossible overflow
            records[(size_t)b * cap + slot] = f;
    }
}

// ---- gather: one block per bucket; LDS-accumulate; out += acc ----
__global__ __launch_bounds__(GAT, 4)
void pol_gather(const f32x4* __restrict__ records,
                const int*   __restrict__ gcursor,
                float*       __restrict__ out,
                int cap, int npb, int n_nodes) {
    __shared__ float acc[3 * MAX_NPB];
    int j   = blockIdx.x;
    int tid = threadIdx.x;
    int n0  = j * npb;
    int nn  = min(npb, n_nodes - n0);
    if (nn <= 0) return;

    for (int k = tid; k < 3 * nn; k += GAT) acc[k] = 0.0f;
    __syncthreads();

    int cnt = min(gcursor[j * GC_STRIDE], cap);
    const f32x4* rec = records + (size_t)j * cap;

    int i = tid;
    // 8x unroll: 8 independent loads in flight per wave
    for (; i + 7 * GAT < cnt; i += 8 * GAT) {
        f32x4 r[8];
        #pragma unroll
        for (int u = 0; u < 8; ++u) r[u] = __builtin_nontemporal_load(&rec[i + u * GAT]);
        #pragma unroll
        for (int u = 0; u < 8; ++u) {
            int l = __float_as_int(r[u].w) - n0;
            atomicAdd(&acc[3*l + 0], r[u].x);
            atomicAdd(&acc[3*l + 1], r[u].y);
            atomicAdd(&acc[3*l + 2], r[u].z);
        }
    }
    for (; i < cnt; i += GAT) {
        f32x4 r = __builtin_nontemporal_load(&rec[i]);
        int l = __float_as_int(r.w) - n0;
        atomicAdd(&acc[3*l + 0], r.x);
        atomicAdd(&acc[3*l + 1], r.y);
        atomicAdd(&acc[3*l + 2], r.z);
    }
    __syncthreads();

    float* o = out + (size_t)3 * n0;
    for (int k = tid; k < 3 * nn; k += GAT) o[k] += acc[k];
}

// ---- fallback (R1): device-scope atomics straight into out ----
__global__ void pol_fb_node(const float* __restrict__ pol_ang,
                            const float* __restrict__ mu,
                            float* __restrict__ out,
                            float* __restrict__ q, int n_nodes) {
    int i = blockIdx.x * blockDim.x + threadIdx.x;
    if (i >= n_nodes) return;
    float pol = pol_ang[i] * INV_BOHR3;
    float ip  = 1.0f / pol;
    out[3*i + 0] = mu[3*i + 0] * ip;
    out[3*i + 1] = mu[3*i + 1] * ip;
    out[3*i + 2] = mu[3*i + 2] * ip;
    q[i] = powf(pol, -1.0f / 6.0f);
}

__global__ void pol_edge_kernel(const int*   __restrict__ src,
                                const int*   __restrict__ dst,
                                const float* __restrict__ dist,
                                const float* __restrict__ vec,
                                const float* __restrict__ q,
                                const float* __restrict__ mu,
                                float* __restrict__ out, int n_edges) {
    int e = blockIdx.x * blockDim.x + threadIdx.x;
    if (e >= n_edges) return;
    int s = src[e], d = dst[e];
    float rij = dist[e] * INV_BOHR;
    float cx, cy, cz;
    thole_contrib(rij, vec[3*e+0]*INV_BOHR, vec[3*e+1]*INV_BOHR, vec[3*e+2]*INV_BOHR,
                  q[s], q[d], mu[3*d+0], mu[3*d+1], mu[3*d+2], cx, cy, cz);
    atomicAdd(&out[3*s + 0], cx);
    atomicAdd(&out[3*s + 1], cy);
    atomicAdd(&out[3*s + 2], cz);
}

extern "C" void kernel_launch(void* const* d_in, const int* in_sizes, int n_in,
                              void* d_out, int out_size, void* d_ws, size_t ws_size,
                              hipStream_t stream) {
    // inputs: 0 species(unused) 1 edge_src 2 edge_dst 3 distances 4 vec 5 polarisability 6 mu
    const int*   edge_src = (const int*)d_in[1];
    const int*   edge_dst = (const int*)d_in[2];
    const float* dist     = (const float*)d_in[3];
    const float* vec      = (const float*)d_in[4];
    const float* pol      = (const float*)d_in[5];
    const float* mu       = (const float*)d_in[6];

    float* out   = (float*)d_out;
    int n_nodes  = in_sizes[5];
    int n_edges  = in_sizes[1];
    int npb      = (n_nodes + NB - 1) / NB;              // nodes per bucket
    unsigned magic = (unsigned)((1ULL << MSHIFT) / (unsigned)npb + 1ULL);  // exact for s<2^18

    // pick smallest NCHUNK whose record buffer fits in ws
    size_t gc_bytes  = (size_t)NB * GC_STRIDE * sizeof(int);     // 16KB padded cursors
    size_t qmu_bytes = (size_t)n_nodes * sizeof(f32x4);
    size_t reserve   = gc_bytes + qmu_bytes + 4096;
    int    nch = -1;
    long long cap = 0;
    size_t rec_bytes = 0;
    for (int c = 1; c <= 16; c *= 2) {
        long long chunk = ((long long)n_edges + c - 1) / c;
        long long m     = (chunk + NB - 1) / NB;
        long long cp    = m + 8 * (long long)(sqrt((double)m) + 1.0) + 64;
        size_t rb = (size_t)NB * (size_t)cp * sizeof(f32x4);
        if (rb + reserve <= ws_size) { nch = c; cap = cp; rec_bytes = rb; break; }
    }

    if (nch > 0 && npb <= MAX_NPB) {
        f32x4* records = (f32x4*)d_ws;
        int*   gcursor = (int*)((char*)d_ws + rec_bytes);
        f32x4* qmu     = (f32x4*)((char*)d_ws + rec_bytes + gc_bytes);

        pol_node_kernel<<<(n_nodes + 255) / 256, 256, 0, stream>>>(pol, mu, out, qmu, n_nodes);

        long long chunk = ((long long)n_edges + nch - 1) / nch;
        for (int r = 0; r < nch; ++r) {
            int e0 = (int)(r * chunk);
            int e1 = (int)min((long long)n_edges, e0 + chunk);
            if (e0 >= e1) break;
            (void)hipMemsetAsync(gcursor, 0, gc_bytes, stream);
            int nblk = (e1 - e0 + EPB - 1) / EPB;
            pol_scatter<<<nblk, SCT, 0, stream>>>(edge_src, edge_dst, dist, vec, qmu,
                                                  records, gcursor, e0, e1, npb, (int)cap, magic);
            pol_gather<<<NB, GAT, 0, stream>>>(records, gcursor, out, (int)cap, npb, n_nodes);
        }
    } else {
        // fallback: R1 atomic path (needs only q in ws)
        float* q = (float*)d_ws;
        pol_fb_node<<<(n_nodes + 255) / 256, 256, 0, stream>>>(pol, mu, out, q, n_nodes);
        pol_edge_kernel<<<(n_edges + 255) / 256, 256, 0, stream>>>(edge_src, edge_dst, dist, vec,
                                                                   q, mu, out, n_edges);
    }
}